// Round 1
// baseline (324.981 us; speedup 1.0000x reference)
//
#include <hip/hip_runtime.h>
#include <hip/hip_fp8.h>

#define LOGZERO -4290774016.0f   // -(65504^2), exactly representable in fp32
#define L2E 1.4426950408889634f  // log2(e)
#define LN2 0.6931471805599453f

constexpr int Bb = 32, Tt = 512, Dd = 512, Vv = 4096;
constexpr int BT = Bb * Tt;

typedef __attribute__((ext_vector_type(4)))  float f32x4;
typedef __attribute__((ext_vector_type(16))) float f32x16;
typedef __attribute__((ext_vector_type(4)))  int   i32x4;
typedef __attribute__((ext_vector_type(8)))  int   i32x8;

#define GLOBAL_AS __attribute__((address_space(1)))
#define LDS_AS    __attribute__((address_space(3)))

__device__ __forceinline__ float fexp2(float x) { return __builtin_amdgcn_exp2f(x); }  // 2^x
__device__ __forceinline__ float flog2(float x) { return __builtin_amdgcn_logf(x); }   // log2(x)

// pack 4 floats (scaled) -> 4 OCP e4m3 bytes
__device__ __forceinline__ unsigned cvt4_fp8(float4 v, float s) {
#if __has_builtin(__builtin_amdgcn_cvt_pk_fp8_f32)
  int p = __builtin_amdgcn_cvt_pk_fp8_f32(v.x * s, v.y * s, 0, false);
  p = __builtin_amdgcn_cvt_pk_fp8_f32(v.z * s, v.w * s, p, true);
  return (unsigned)p;
#else
  unsigned b0 = __hip_cvt_float_to_fp8(v.x * s, __HIP_SATFINITE, __HIP_E4M3);
  unsigned b1 = __hip_cvt_float_to_fp8(v.y * s, __HIP_SATFINITE, __HIP_E4M3);
  unsigned b2 = __hip_cvt_float_to_fp8(v.z * s, __HIP_SATFINITE, __HIP_E4M3);
  unsigned b3 = __hip_cvt_float_to_fp8(v.w * s, __HIP_SATFINITE, __HIP_E4M3);
  return b0 | (b1 << 8) | (b2 << 16) | (b3 << 24);
#endif
}

// logaddexp in the log2 domain
__device__ __forceinline__ float lg2add(float a, float b) {
  float mx = fmaxf(a, b);
  float d  = fabsf(a - b);
  return mx + flog2(1.0f + fexp2(-d));
}

// ---- kPre: pack x and W into fp8 FRAGMENT-ORDER layouts for 32x32x64 MFMA ----
// Fragment need (mfma_scale_f32_32x32x64_f8f6f4): lane l supplies row/col (l&31),
// k = kb*64 + (l>>5)*32 + [0..32) as 32 contiguous bytes (8 VGPRs).
// Storage: 1 KB slots of 64 lanes x 16 B; lane's 32 B split across two adjacent
// slots (h=0: k+[0,16), h=1: k+[16,32)) so kA staging stays linear 1 KB DMA
// bursts and ds_read_b128 at lane*16 stays conflict-free.
// Xfp slot: tM*32768 + ((kb*2+rt)*2+h)*1024 + l*16
//   = fp8( x[tM*64 + rt*32 + (l&31)][kb*64 + (l>>5)*32 + h*16 + j] ), j=0..15
// Wp  slot: cb*32768 + ((kb*2+ct)*2+h)*1024 + l*16
//   = fp8( 16 * W[cb*64 + ct*32 + (l&31)][kb*64 + (l>>5)*32 + h*16 + j] )
// Thread t <-> output slot t: writes perfectly coalesced (16 B consecutive);
// reads are one 64 B contiguous row-chunk per thread.
__global__ __launch_bounds__(256) void kPre(const float* __restrict__ x,
                                            const float* __restrict__ W,
                                            unsigned char* __restrict__ Xfp,
                                            unsigned char* __restrict__ Wp) {
  const int t = blockIdx.x * 256 + threadIdx.x;
  if (t < 524288) {                     // X part: 8 MB / 16 B = 524288 slots
    const int tM = t >> 11, s = t & 2047;
    const int l = s & 63, h = (s >> 6) & 1, rt = (s >> 7) & 1, kb = s >> 8;
    const int row = tM * 64 + rt * 32 + (l & 31);
    const int col = kb * 64 + ((l >> 5) << 5) + h * 16;
    const float* p = x + (size_t)row * Dd + col;
    uint4 o;
    o.x = cvt4_fp8(*(const float4*)p, 1.0f);
    o.y = cvt4_fp8(*(const float4*)(p + 4), 1.0f);
    o.z = cvt4_fp8(*(const float4*)(p + 8), 1.0f);
    o.w = cvt4_fp8(*(const float4*)(p + 12), 1.0f);
    *(uint4*)(Xfp + (size_t)t * 16) = o;
  } else {                              // W part: 2 MB / 16 B = 131072 slots
    const int tt = t - 524288;
    const int cb = tt >> 11, s = tt & 2047;
    const int l = s & 63, h = (s >> 6) & 1, ct = (s >> 7) & 1, kb = s >> 8;
    const int row = cb * 64 + ct * 32 + (l & 31);
    const int col = kb * 64 + ((l >> 5) << 5) + h * 16;
    const float* p = W + (size_t)row * Dd + col;
    uint4 o;
    o.x = cvt4_fp8(*(const float4*)p, 16.0f);       // x16 prescale into e4m3 range
    o.y = cvt4_fp8(*(const float4*)(p + 4), 16.0f); // (undone by MX scale_b = 2^-4)
    o.z = cvt4_fp8(*(const float4*)(p + 8), 16.0f);
    o.w = cvt4_fp8(*(const float4*)(p + 12), 16.0f);
    *(uint4*)(Wp + (size_t)tt * 16) = o;
  }
}

// ---- barrier-free MX-fp8 GEMM + exp-sum partials + beam scatter, M_tile=64 ----
// grid 4096, 256 threads (4 waves). Block = 64 rows x 256 cols, full K=512.
// mfma_scale_f32_32x32x64_f8f6f4: 32 MFMA/wave (8 k-steps x 2x2 tiles) at the
// MX rate (~4.7 PF ceiling vs 2.1 PF for non-scaled fp8). scale_a = 1.0
// (e8m0 127), scale_b = 2^-4 (e8m0 123) folds away the W x16 prescale, so
// acc holds TRUE logits (no 0.0625 dequant in the epilogues).
// A = 32 KB packed LDS (linear 1KB DMA bursts, conflict-free ds_read_b128);
// B = 4 dwordx4 global loads/k-step, depth-1 prefetch, zero K-loop barriers,
// full unroll. acc(64)+afrag(16)+b cur/pre(32) ~ 112 VGPR -> 4 blocks/CU.
__global__ __launch_bounds__(256, 4) void kA(const unsigned char* __restrict__ Xfp,
                                             const unsigned char* __restrict__ Wp,
                                             const float* __restrict__ bias,
                                             const int* __restrict__ beam,
                                             const int* __restrict__ blankp,
                                             float* __restrict__ Spart,
                                             float* __restrict__ selL,
                                             int CB) {
  __shared__ unsigned char Ald[32768];   // packed A tile (64 rows x 512 K)
  __shared__ float Spw[4][64];
  __shared__ int   selv[31];
  __shared__ float selb[31];

  const int tid = threadIdx.x;
  const int tileN = blockIdx.x & 15;
  const int tileM = blockIdx.x >> 4;
  const int row0 = tileM * 64, col0 = tileN * 256;
  const int bb = row0 >> 9;              // batch of this block (64 | 512)
  const int lane = tid & 63, w = tid >> 6;
  const int l31 = lane & 31, hi = lane >> 5;

  if (tid < 31) {
    int v = (tid == 0) ? *blankp : beam[bb * CB + tid - 1];
    selv[tid] = v;
    selb[tid] = bias[v];
  }

  // stage packed A tile: 32 x 1KB fully-linear DMA bursts (wave w does 8)
  const unsigned char* src = Xfp + (size_t)tileM * 32768;
  #pragma unroll
  for (int i = 0; i < 8; ++i) {
    int off = (w * 8 + i) * 1024;
    __builtin_amdgcn_global_load_lds((const GLOBAL_AS void*)(src + off + lane * 16),
                                     (LDS_AS void*)(Ald + off), 16, 0, 0);
  }
  __syncthreads();                       // only barrier before epilogue

  const int colw = col0 + w * 64;
  const int cb = tileN * 4 + w;

  f32x16 acc[2][2];                      // acc[ct][rt]
  #pragma unroll
  for (int ct = 0; ct < 2; ++ct)
    #pragma unroll
    for (int rt = 0; rt < 2; ++rt)
      #pragma unroll
      for (int r = 0; r < 16; ++r) acc[ct][rt][r] = 0.f;

  const unsigned char* wpB = Wp + (size_t)cb * 32768 + lane * 16;

  i32x8 bc[2];
  #pragma unroll
  for (int ct = 0; ct < 2; ++ct) {
    i32x4 lo = *(const i32x4*)(wpB + (ct * 2) * 1024);
    i32x4 hx = *(const i32x4*)(wpB + (ct * 2 + 1) * 1024);
    bc[ct] = __builtin_shufflevector(lo, hx, 0, 1, 2, 3, 4, 5, 6, 7);
  }

  #pragma unroll
  for (int kb = 0; kb < 8; ++kb) {
    i32x8 af[2];
    #pragma unroll
    for (int rt = 0; rt < 2; ++rt) {     // linear conflict-free b128 pairs
      i32x4 lo = *(const i32x4*)&Ald[(kb * 4 + rt * 2) * 1024 + lane * 16];
      i32x4 hx = *(const i32x4*)&Ald[(kb * 4 + rt * 2 + 1) * 1024 + lane * 16];
      af[rt] = __builtin_shufflevector(lo, hx, 0, 1, 2, 3, 4, 5, 6, 7);
    }
    i32x8 bn[2];
    const int kn = (kb < 7) ? kb + 1 : 7;   // depth-1 B prefetch
    #pragma unroll
    for (int ct = 0; ct < 2; ++ct) {
      i32x4 lo = *(const i32x4*)(wpB + (kn * 4 + ct * 2) * 1024);
      i32x4 hx = *(const i32x4*)(wpB + (kn * 4 + ct * 2 + 1) * 1024);
      bn[ct] = __builtin_shufflevector(lo, hx, 0, 1, 2, 3, 4, 5, 6, 7);
    }
    #pragma unroll
    for (int ct = 0; ct < 2; ++ct)
      #pragma unroll
      for (int rt = 0; rt < 2; ++rt)
        acc[ct][rt] = __builtin_amdgcn_mfma_scale_f32_32x32x64_f8f6f4(
            af[rt], bc[ct], acc[ct][rt],
            0, 0,                         // cbsz=fp8(A), blgp=fp8(B)
            0, 0x7f7f7f7f,                // scale_a = 2^0  (e8m0 127)
            0, 0x7b7b7b7b);               // scale_b = 2^-4 (e8m0 123)
    bc[0] = bn[0]; bc[1] = bn[1];
  }

  // epilogue 1: row-wise sum(exp(logit+bias)) -> per-block partial (no atomics)
  // C layout (32x32): col = ct*32 + l31, row = rt*32 + (reg&3) + 8*(reg>>2) + 4*hi
  float bvl[2];
  #pragma unroll
  for (int ct = 0; ct < 2; ++ct)
    bvl[ct] = bias[colw + ct * 32 + l31] * L2E;

  #pragma unroll
  for (int rt = 0; rt < 2; ++rt) {
    #pragma unroll
    for (int reg = 0; reg < 16; ++reg) {
      float s = fexp2(acc[0][rt][reg] * L2E + bvl[0]) +
                fexp2(acc[1][rt][reg] * L2E + bvl[1]);
      s += __shfl_xor(s, 1, 64);          // reduce over 32 cols (lane bits 0..4;
      s += __shfl_xor(s, 2, 64);          //  hi-bit lanes hold different rows,
      s += __shfl_xor(s, 4, 64);          //  never mixed by this tree)
      s += __shfl_xor(s, 8, 64);
      s += __shfl_xor(s, 16, 64);
      if (l31 == 0)
        Spw[w][rt * 32 + (reg & 3) + 8 * (reg >> 2) + 4 * hi] = s;
    }
  }
  __syncthreads();
  if (tid < 64) {
    float p = Spw[0][tid] + Spw[1][tid] + Spw[2][tid] + Spw[3][tid];
    Spart[(size_t)tileN * BT + row0 + tid] = p;
  }

  // epilogue 2: beam-column scatter (raw ln-domain logit + bias)
  const int tbase = row0 & 511;
  for (int s = 0; s < 31; ++s) {
    int local = selv[s] - colw;
    #pragma unroll
    for (int ct = 0; ct < 2; ++ct) {      // static ct: keeps acc in registers
      if (local >= ct * 32 && local < (ct + 1) * 32 && l31 == (local & 31)) {
        float bvs = selb[s];
        #pragma unroll
        for (int rt = 0; rt < 2; ++rt)
          #pragma unroll
          for (int reg = 0; reg < 16; ++reg) {
            int t = tbase + rt * 32 + (reg & 3) + 8 * (reg >> 2) + 4 * hi;
            selL[((size_t)bb * Tt + t) * 31 + s] = acc[ct][rt][reg] + bvs;
          }
      }
    }
  }
}

// ---- CTC DP + output assembly, log2 domain. grid: B blocks x 256 threads ----
__global__ __launch_bounds__(256) void kC(const float* __restrict__ selL,
                                          const float* __restrict__ Spart,
                                          const int* __restrict__ xl,
                                          const int* __restrict__ beam,
                                          const int* __restrict__ blankp,
                                          const int* __restrict__ eosp,
                                          float* __restrict__ out,
                                          int Ly, int CB) {
  __shared__ float sl[Tt * 31];     // raw logits * log2(e)
  __shared__ float lgS[Tt];         // log2(sum_exp)
  __shared__ float lastP1[Tt];      // log2-domain blank cumsum
  __shared__ float blankLp[Tt];     // log2-domain blank logp
  const int b = blockIdx.x, tid = threadIdx.x;

  for (int i = tid; i < Tt * 31; i += 256)
    sl[i] = selL[(size_t)b * Tt * 31 + i] * L2E;
  for (int tt = tid; tt < Tt; tt += 256) {
    float s = 0.f;
    #pragma unroll
    for (int n = 0; n < 16; ++n) s += Spart[(size_t)n * BT + b * Tt + tt];
    lgS[tt] = flog2(s);
  }
  __syncthreads();

  float* orow = out + (size_t)b * Vv;
  for (int i = tid; i < Vv; i += 256) orow[i] = LOGZERO;

  const int xlb = xl[b];
  float curP = LOGZERO;
  if (tid < 64) {
    const int lane = tid;
    float vloc[8];
    float run = 0.f;
    #pragma unroll
    for (int u = 0; u < 8; ++u) {
      int t = lane * 8 + u;
      float bl = sl[t * 31] - lgS[t];
      blankLp[t] = bl;
      run += bl;
      vloc[u] = run;
    }
    float inc = run;
    #pragma unroll
    for (int off = 1; off < 64; off <<= 1) {
      float o = __shfl_up(inc, off, 64);
      if (lane >= off) inc += o;
    }
    float excl = inc - run;
    #pragma unroll
    for (int u = 0; u < 8; ++u) lastP1[lane * 8 + u] = vloc[u] + excl;

    const int kk = (lane < CB) ? lane : (CB - 1);
    const float LOG2ZERO = LOGZERO * L2E;
    float Pn = LOG2ZERO, Pb = LOG2ZERO;
    float mrun = -3.0e38f, srun = 0.0f;
    int start = (Ly < Tt - 1) ? Ly : (Tt - 1);
    if (start == 0) {
      Pn = sl[1 + kk] - lgS[0];
      float vv = (0 < xlb) ? lg2add(Pn, Pb) : LOG2ZERO;
      float nm = fmaxf(mrun, vv);
      srun = srun * fexp2(mrun - nm) + fexp2(vv - nm);
      mrun = nm;
    }
    int t0 = (start > 1) ? start : 1;
    #pragma unroll 2
    for (int t = t0; t < Tt; ++t) {
      float xn = sl[t * 31 + 1 + kk] - lgS[t];
      float xb = blankLp[t];
      float pref = lastP1[t - 1];   // lastPsum == lastP1 bit-exactly
      float Pn2 = lg2add(Pn, pref) + xn;
      float Pb2 = lg2add(Pn, Pb) + xb;
      Pn = Pn2; Pb = Pb2;
      float vv = (t < xlb) ? lg2add(Pn, Pb) : LOG2ZERO;   // off critical path
      float nm = fmaxf(mrun, vv);
      srun = srun * fexp2(mrun - nm) + fexp2(vv - nm);
      mrun = nm;
    }
    curP = (mrun + flog2(srun)) * LN2;       // back to ln domain
  }
  __syncthreads();   // LOGZERO fill + lastP1 complete

  if (tid < 64) {
    if (tid < CB) orow[beam[b * CB + tid]] = curP;
  }
  __syncthreads();
  if (tid == 0) {
    float eosv = (xlb >= 1) ? lastP1[xlb - 1] * LN2 : 0.0f;
    orow[*eosp] = eosv;
    orow[*blankp] = LOGZERO;
  }
}

extern "C" void kernel_launch(void* const* d_in, const int* in_sizes, int n_in,
                              void* d_out, int out_size, void* d_ws, size_t ws_size,
                              hipStream_t stream) {
  (void)n_in; (void)out_size; (void)ws_size;
  const float* x    = (const float*)d_in[0];
  const float* W    = (const float*)d_in[1];
  const float* bias = (const float*)d_in[2];
  const int* xl     = (const int*)d_in[3];
  const int* beam   = (const int*)d_in[5];
  const int* blankp = (const int*)d_in[6];
  const int* eosp   = (const int*)d_in[7];
  const int Ly = in_sizes[4] / Bb;
  const int CB = in_sizes[5] / Bb;

  float* Spart = (float*)d_ws;                                            // 1 MB
  float* selL  = (float*)((char*)d_ws + (size_t)0x100000);                // 2.03 MB
  unsigned char* Xfp = (unsigned char*)((char*)d_ws + (size_t)0x400000);  // 8 MB
  unsigned char* Wp  = (unsigned char*)((char*)d_ws + (size_t)0xC00000);  // 2 MB
  float* outf = (float*)d_out;

  kPre<<<2560, 256, 0, stream>>>(x, W, Xfp, Wp);
  kA<<<4096, 256, 0, stream>>>(Xfp, Wp, bias, beam, blankp, Spart, selL, CB);
  kC<<<Bb, 256, 0, stream>>>(selL, Spart, xl, beam, blankp, eosp, outf, Ly, CB);
}

// Round 2
// 297.414 us; speedup vs baseline: 1.0927x; 1.0927x over previous
//
#include <hip/hip_runtime.h>
#include <hip/hip_fp8.h>

#define LOGZERO -4290774016.0f   // -(65504^2), exactly representable in fp32
#define L2E 1.4426950408889634f  // log2(e)
#define LN2 0.6931471805599453f

constexpr int Bb = 32, Tt = 512, Dd = 512, Vv = 4096;
constexpr int BT = Bb * Tt;

typedef __attribute__((ext_vector_type(4)))  float f32x4;
typedef __attribute__((ext_vector_type(16))) float f32x16;
typedef __attribute__((ext_vector_type(4)))  int   i32x4;
typedef __attribute__((ext_vector_type(8)))  int   i32x8;

#define GLOBAL_AS __attribute__((address_space(1)))
#define LDS_AS    __attribute__((address_space(3)))

__device__ __forceinline__ float fexp2(float x) { return __builtin_amdgcn_exp2f(x); }  // 2^x
__device__ __forceinline__ float flog2(float x) { return __builtin_amdgcn_logf(x); }   // log2(x)

// pack 4 floats (scaled) -> 4 OCP e4m3 bytes
__device__ __forceinline__ unsigned cvt4_fp8(float4 v, float s) {
#if __has_builtin(__builtin_amdgcn_cvt_pk_fp8_f32)
  int p = __builtin_amdgcn_cvt_pk_fp8_f32(v.x * s, v.y * s, 0, false);
  p = __builtin_amdgcn_cvt_pk_fp8_f32(v.z * s, v.w * s, p, true);
  return (unsigned)p;
#else
  unsigned b0 = __hip_cvt_float_to_fp8(v.x * s, __HIP_SATFINITE, __HIP_E4M3);
  unsigned b1 = __hip_cvt_float_to_fp8(v.y * s, __HIP_SATFINITE, __HIP_E4M3);
  unsigned b2 = __hip_cvt_float_to_fp8(v.z * s, __HIP_SATFINITE, __HIP_E4M3);
  unsigned b3 = __hip_cvt_float_to_fp8(v.w * s, __HIP_SATFINITE, __HIP_E4M3);
  return b0 | (b1 << 8) | (b2 << 16) | (b3 << 24);
#endif
}

// logaddexp in the log2 domain
__device__ __forceinline__ float lg2add(float a, float b) {
  float mx = fmaxf(a, b);
  float d  = fabsf(a - b);
  return mx + flog2(1.0f + fexp2(-d));
}

// ---- kPre: pack x and W into fp8 FRAGMENT-ORDER layouts for 32x32x64 MFMA ----
// Fragment need (mfma_scale_f32_32x32x64_f8f6f4): lane l supplies row/col (l&31),
// k = kb*64 + (l>>5)*32 + [0..32) as 32 contiguous bytes (8 VGPRs).
// Storage: 1 KB slots of 64 lanes x 16 B; lane's 32 B split across two adjacent
// slots (h=0: k+[0,16), h=1: k+[16,32)) so kA staging stays linear 1 KB DMA
// bursts and ds_read_b128 at lane*16 stays conflict-free.
// Xfp slot: tM*32768 + ((kb*2+rt)*2+h)*1024 + l*16
//   = fp8( x[tM*64 + rt*32 + (l&31)][kb*64 + (l>>5)*32 + h*16 + j] ), j=0..15
// Wp  slot: cb*32768 + ((kb*2+ct)*2+h)*1024 + l*16
//   = fp8( 16 * W[cb*64 + ct*32 + (l&31)][kb*64 + (l>>5)*32 + h*16 + j] )
// Thread t <-> output slot t: writes perfectly coalesced (16 B consecutive);
// reads are one 64 B contiguous row-chunk per thread.
__global__ __launch_bounds__(256) void kPre(const float* __restrict__ x,
                                            const float* __restrict__ W,
                                            unsigned char* __restrict__ Xfp,
                                            unsigned char* __restrict__ Wp) {
  const int t = blockIdx.x * 256 + threadIdx.x;
  if (t < 524288) {                     // X part: 8 MB / 16 B = 524288 slots
    const int tM = t >> 11, s = t & 2047;
    const int l = s & 63, h = (s >> 6) & 1, rt = (s >> 7) & 1, kb = s >> 8;
    const int row = tM * 64 + rt * 32 + (l & 31);
    const int col = kb * 64 + ((l >> 5) << 5) + h * 16;
    const float* p = x + (size_t)row * Dd + col;
    uint4 o;
    o.x = cvt4_fp8(*(const float4*)p, 1.0f);
    o.y = cvt4_fp8(*(const float4*)(p + 4), 1.0f);
    o.z = cvt4_fp8(*(const float4*)(p + 8), 1.0f);
    o.w = cvt4_fp8(*(const float4*)(p + 12), 1.0f);
    *(uint4*)(Xfp + (size_t)t * 16) = o;
  } else {                              // W part: 2 MB / 16 B = 131072 slots
    const int tt = t - 524288;
    const int cb = tt >> 11, s = tt & 2047;
    const int l = s & 63, h = (s >> 6) & 1, ct = (s >> 7) & 1, kb = s >> 8;
    const int row = cb * 64 + ct * 32 + (l & 31);
    const int col = kb * 64 + ((l >> 5) << 5) + h * 16;
    const float* p = W + (size_t)row * Dd + col;
    uint4 o;
    o.x = cvt4_fp8(*(const float4*)p, 16.0f);       // x16 prescale into e4m3 range
    o.y = cvt4_fp8(*(const float4*)(p + 4), 16.0f); // (undone by MX scale_b = 2^-4)
    o.z = cvt4_fp8(*(const float4*)(p + 8), 16.0f);
    o.w = cvt4_fp8(*(const float4*)(p + 12), 16.0f);
    *(uint4*)(Wp + (size_t)tt * 16) = o;
  }
}

// ---- barrier-free MX-fp8 GEMM + exp-sum partials + beam scatter, M_tile=64 ----
// grid 4096, 256 threads (4 waves). Block = 64 rows x 256 cols, full K=512.
// mfma_scale_f32_32x32x64_f8f6f4: 32 MFMA/wave (8 k-steps x 2x2 tiles) at the
// MX rate (~4.7 PF ceiling vs 2.1 PF for non-scaled fp8). scale_a = 1.0
// (e8m0 127), scale_b = 2^-4 (e8m0 123) folds away the W x16 prescale, so
// acc holds TRUE logits (no 0.0625 dequant in the epilogues).
// A = 32 KB packed LDS (linear 1KB DMA bursts, conflict-free ds_read_b128);
// B = 4 dwordx4 global loads/k-step, depth-1 prefetch, zero K-loop barriers,
// full unroll.
// REGISTER BUDGET (round-1 lesson): acc 64 AGPR + af 16 + bc 16 + bn 16 +
// ~20 addr/temps ~ 132-150 regs. __launch_bounds__(256,4) caps at 128 ->
// the allocator spilled the K-loop working set (WRITE_SIZE 11->538 MB,
// MfmaUtil 7%). (256,3) caps at ~170 -> spill-free, 3 blocks/CU.
__global__ __launch_bounds__(256, 3) void kA(const unsigned char* __restrict__ Xfp,
                                             const unsigned char* __restrict__ Wp,
                                             const float* __restrict__ bias,
                                             const int* __restrict__ beam,
                                             const int* __restrict__ blankp,
                                             float* __restrict__ Spart,
                                             float* __restrict__ selL,
                                             int CB) {
  __shared__ unsigned char Ald[32768];   // packed A tile (64 rows x 512 K)
  __shared__ float Spw[4][64];
  __shared__ int   selv[31];
  __shared__ float selb[31];

  const int tid = threadIdx.x;
  const int tileN = blockIdx.x & 15;
  const int tileM = blockIdx.x >> 4;
  const int row0 = tileM * 64, col0 = tileN * 256;
  const int bb = row0 >> 9;              // batch of this block (64 | 512)
  const int lane = tid & 63, w = tid >> 6;
  const int l31 = lane & 31, hi = lane >> 5;

  if (tid < 31) {
    int v = (tid == 0) ? *blankp : beam[bb * CB + tid - 1];
    selv[tid] = v;
    selb[tid] = bias[v];
  }

  // stage packed A tile: 32 x 1KB fully-linear DMA bursts (wave w does 8)
  const unsigned char* src = Xfp + (size_t)tileM * 32768;
  #pragma unroll
  for (int i = 0; i < 8; ++i) {
    int off = (w * 8 + i) * 1024;
    __builtin_amdgcn_global_load_lds((const GLOBAL_AS void*)(src + off + lane * 16),
                                     (LDS_AS void*)(Ald + off), 16, 0, 0);
  }
  __syncthreads();                       // only barrier before epilogue

  const int colw = col0 + w * 64;
  const int cb = tileN * 4 + w;

  f32x16 acc[2][2];                      // acc[ct][rt]
  #pragma unroll
  for (int ct = 0; ct < 2; ++ct)
    #pragma unroll
    for (int rt = 0; rt < 2; ++rt)
      #pragma unroll
      for (int r = 0; r < 16; ++r) acc[ct][rt][r] = 0.f;

  const unsigned char* wpB = Wp + (size_t)cb * 32768 + lane * 16;

  i32x8 bc[2];
  #pragma unroll
  for (int ct = 0; ct < 2; ++ct) {
    i32x4 lo = *(const i32x4*)(wpB + (ct * 2) * 1024);
    i32x4 hx = *(const i32x4*)(wpB + (ct * 2 + 1) * 1024);
    bc[ct] = __builtin_shufflevector(lo, hx, 0, 1, 2, 3, 4, 5, 6, 7);
  }

  #pragma unroll
  for (int kb = 0; kb < 8; ++kb) {
    i32x8 af[2];
    #pragma unroll
    for (int rt = 0; rt < 2; ++rt) {     // linear conflict-free b128 pairs
      i32x4 lo = *(const i32x4*)&Ald[(kb * 4 + rt * 2) * 1024 + lane * 16];
      i32x4 hx = *(const i32x4*)&Ald[(kb * 4 + rt * 2 + 1) * 1024 + lane * 16];
      af[rt] = __builtin_shufflevector(lo, hx, 0, 1, 2, 3, 4, 5, 6, 7);
    }
    i32x8 bn[2];
    const int kn = (kb < 7) ? kb + 1 : 7;   // depth-1 B prefetch
    #pragma unroll
    for (int ct = 0; ct < 2; ++ct) {
      i32x4 lo = *(const i32x4*)(wpB + (kn * 4 + ct * 2) * 1024);
      i32x4 hx = *(const i32x4*)(wpB + (kn * 4 + ct * 2 + 1) * 1024);
      bn[ct] = __builtin_shufflevector(lo, hx, 0, 1, 2, 3, 4, 5, 6, 7);
    }
    #pragma unroll
    for (int ct = 0; ct < 2; ++ct)
      #pragma unroll
      for (int rt = 0; rt < 2; ++rt)
        acc[ct][rt] = __builtin_amdgcn_mfma_scale_f32_32x32x64_f8f6f4(
            af[rt], bc[ct], acc[ct][rt],
            0, 0,                         // cbsz=fp8(A), blgp=fp8(B)
            0, 0x7f7f7f7f,                // scale_a = 2^0  (e8m0 127)
            0, 0x7b7b7b7b);               // scale_b = 2^-4 (e8m0 123)
    bc[0] = bn[0]; bc[1] = bn[1];
  }

  // epilogue 1: row-wise sum(exp(logit+bias)) -> per-block partial (no atomics)
  // C layout (32x32): col = ct*32 + l31, row = rt*32 + (reg&3) + 8*(reg>>2) + 4*hi
  float bvl[2];
  #pragma unroll
  for (int ct = 0; ct < 2; ++ct)
    bvl[ct] = bias[colw + ct * 32 + l31] * L2E;

  #pragma unroll
  for (int rt = 0; rt < 2; ++rt) {
    #pragma unroll
    for (int reg = 0; reg < 16; ++reg) {
      float s = fexp2(acc[0][rt][reg] * L2E + bvl[0]) +
                fexp2(acc[1][rt][reg] * L2E + bvl[1]);
      s += __shfl_xor(s, 1, 64);          // reduce over 32 cols (lane bits 0..4;
      s += __shfl_xor(s, 2, 64);          //  hi-bit lanes hold different rows,
      s += __shfl_xor(s, 4, 64);          //  never mixed by this tree)
      s += __shfl_xor(s, 8, 64);
      s += __shfl_xor(s, 16, 64);
      if (l31 == 0)
        Spw[w][rt * 32 + (reg & 3) + 8 * (reg >> 2) + 4 * hi] = s;
    }
  }
  __syncthreads();
  if (tid < 64) {
    float p = Spw[0][tid] + Spw[1][tid] + Spw[2][tid] + Spw[3][tid];
    Spart[(size_t)tileN * BT + row0 + tid] = p;
  }

  // epilogue 2: beam-column scatter (raw ln-domain logit + bias)
  const int tbase = row0 & 511;
  for (int s = 0; s < 31; ++s) {
    int local = selv[s] - colw;
    #pragma unroll
    for (int ct = 0; ct < 2; ++ct) {      // static ct: keeps acc in registers
      if (local >= ct * 32 && local < (ct + 1) * 32 && l31 == (local & 31)) {
        float bvs = selb[s];
        #pragma unroll
        for (int rt = 0; rt < 2; ++rt)
          #pragma unroll
          for (int reg = 0; reg < 16; ++reg) {
            int t = tbase + rt * 32 + (reg & 3) + 8 * (reg >> 2) + 4 * hi;
            selL[((size_t)bb * Tt + t) * 31 + s] = acc[ct][rt][reg] + bvs;
          }
      }
    }
  }
}

// ---- CTC DP + output assembly, log2 domain. grid: B blocks x 256 threads ----
__global__ __launch_bounds__(256) void kC(const float* __restrict__ selL,
                                          const float* __restrict__ Spart,
                                          const int* __restrict__ xl,
                                          const int* __restrict__ beam,
                                          const int* __restrict__ blankp,
                                          const int* __restrict__ eosp,
                                          float* __restrict__ out,
                                          int Ly, int CB) {
  __shared__ float sl[Tt * 31];     // raw logits * log2(e)
  __shared__ float lgS[Tt];         // log2(sum_exp)
  __shared__ float lastP1[Tt];      // log2-domain blank cumsum
  __shared__ float blankLp[Tt];     // log2-domain blank logp
  const int b = blockIdx.x, tid = threadIdx.x;

  for (int i = tid; i < Tt * 31; i += 256)
    sl[i] = selL[(size_t)b * Tt * 31 + i] * L2E;
  for (int tt = tid; tt < Tt; tt += 256) {
    float s = 0.f;
    #pragma unroll
    for (int n = 0; n < 16; ++n) s += Spart[(size_t)n * BT + b * Tt + tt];
    lgS[tt] = flog2(s);
  }
  __syncthreads();

  float* orow = out + (size_t)b * Vv;
  for (int i = tid; i < Vv; i += 256) orow[i] = LOGZERO;

  const int xlb = xl[b];
  float curP = LOGZERO;
  if (tid < 64) {
    const int lane = tid;
    float vloc[8];
    float run = 0.f;
    #pragma unroll
    for (int u = 0; u < 8; ++u) {
      int t = lane * 8 + u;
      float bl = sl[t * 31] - lgS[t];
      blankLp[t] = bl;
      run += bl;
      vloc[u] = run;
    }
    float inc = run;
    #pragma unroll
    for (int off = 1; off < 64; off <<= 1) {
      float o = __shfl_up(inc, off, 64);
      if (lane >= off) inc += o;
    }
    float excl = inc - run;
    #pragma unroll
    for (int u = 0; u < 8; ++u) lastP1[lane * 8 + u] = vloc[u] + excl;

    const int kk = (lane < CB) ? lane : (CB - 1);
    const float LOG2ZERO = LOGZERO * L2E;
    float Pn = LOG2ZERO, Pb = LOG2ZERO;
    float mrun = -3.0e38f, srun = 0.0f;
    int start = (Ly < Tt - 1) ? Ly : (Tt - 1);
    if (start == 0) {
      Pn = sl[1 + kk] - lgS[0];
      float vv = (0 < xlb) ? lg2add(Pn, Pb) : LOG2ZERO;
      float nm = fmaxf(mrun, vv);
      srun = srun * fexp2(mrun - nm) + fexp2(vv - nm);
      mrun = nm;
    }
    int t0 = (start > 1) ? start : 1;
    #pragma unroll 2
    for (int t = t0; t < Tt; ++t) {
      float xn = sl[t * 31 + 1 + kk] - lgS[t];
      float xb = blankLp[t];
      float pref = lastP1[t - 1];   // lastPsum == lastP1 bit-exactly
      float Pn2 = lg2add(Pn, pref) + xn;
      float Pb2 = lg2add(Pn, Pb) + xb;
      Pn = Pn2; Pb = Pb2;
      float vv = (t < xlb) ? lg2add(Pn, Pb) : LOG2ZERO;   // off critical path
      float nm = fmaxf(mrun, vv);
      srun = srun * fexp2(mrun - nm) + fexp2(vv - nm);
      mrun = nm;
    }
    curP = (mrun + flog2(srun)) * LN2;       // back to ln domain
  }
  __syncthreads();   // LOGZERO fill + lastP1 complete

  if (tid < 64) {
    if (tid < CB) orow[beam[b * CB + tid]] = curP;
  }
  __syncthreads();
  if (tid == 0) {
    float eosv = (xlb >= 1) ? lastP1[xlb - 1] * LN2 : 0.0f;
    orow[*eosp] = eosv;
    orow[*blankp] = LOGZERO;
  }
}

extern "C" void kernel_launch(void* const* d_in, const int* in_sizes, int n_in,
                              void* d_out, int out_size, void* d_ws, size_t ws_size,
                              hipStream_t stream) {
  (void)n_in; (void)out_size; (void)ws_size;
  const float* x    = (const float*)d_in[0];
  const float* W    = (const float*)d_in[1];
  const float* bias = (const float*)d_in[2];
  const int* xl     = (const int*)d_in[3];
  const int* beam   = (const int*)d_in[5];
  const int* blankp = (const int*)d_in[6];
  const int* eosp   = (const int*)d_in[7];
  const int Ly = in_sizes[4] / Bb;
  const int CB = in_sizes[5] / Bb;

  float* Spart = (float*)d_ws;                                            // 1 MB
  float* selL  = (float*)((char*)d_ws + (size_t)0x100000);                // 2.03 MB
  unsigned char* Xfp = (unsigned char*)((char*)d_ws + (size_t)0x400000);  // 8 MB
  unsigned char* Wp  = (unsigned char*)((char*)d_ws + (size_t)0xC00000);  // 2 MB
  float* outf = (float*)d_out;

  kPre<<<2560, 256, 0, stream>>>(x, W, Xfp, Wp);
  kA<<<4096, 256, 0, stream>>>(Xfp, Wp, bias, beam, blankp, Spart, selL, CB);
  kC<<<Bb, 256, 0, stream>>>(selL, Spart, xl, beam, blankp, eosp, outf, Ly, CB);
}

// Round 3
// 254.023 us; speedup vs baseline: 1.2793x; 1.1708x over previous
//
#include <hip/hip_runtime.h>
#include <hip/hip_fp8.h>

#define LOGZERO -4290774016.0f   // -(65504^2), exactly representable in fp32
#define L2E 1.4426950408889634f  // log2(e)
#define LN2 0.6931471805599453f

constexpr int Bb = 32, Tt = 512, Dd = 512, Vv = 4096;
constexpr int BT = Bb * Tt;

typedef __attribute__((ext_vector_type(4)))  float f32x4;
typedef __attribute__((ext_vector_type(16))) float f32x16;
typedef __attribute__((ext_vector_type(4)))  int   i32x4;
typedef __attribute__((ext_vector_type(8)))  int   i32x8;

#define GLOBAL_AS __attribute__((address_space(1)))
#define LDS_AS    __attribute__((address_space(3)))

__device__ __forceinline__ float fexp2(float x) { return __builtin_amdgcn_exp2f(x); }  // 2^x
__device__ __forceinline__ float flog2(float x) { return __builtin_amdgcn_logf(x); }   // log2(x)

// pack 4 floats (scaled) -> 4 OCP e4m3 bytes
__device__ __forceinline__ unsigned cvt4_fp8(float4 v, float s) {
#if __has_builtin(__builtin_amdgcn_cvt_pk_fp8_f32)
  int p = __builtin_amdgcn_cvt_pk_fp8_f32(v.x * s, v.y * s, 0, false);
  p = __builtin_amdgcn_cvt_pk_fp8_f32(v.z * s, v.w * s, p, true);
  return (unsigned)p;
#else
  unsigned b0 = __hip_cvt_float_to_fp8(v.x * s, __HIP_SATFINITE, __HIP_E4M3);
  unsigned b1 = __hip_cvt_float_to_fp8(v.y * s, __HIP_SATFINITE, __HIP_E4M3);
  unsigned b2 = __hip_cvt_float_to_fp8(v.z * s, __HIP_SATFINITE, __HIP_E4M3);
  unsigned b3 = __hip_cvt_float_to_fp8(v.w * s, __HIP_SATFINITE, __HIP_E4M3);
  return b0 | (b1 << 8) | (b2 << 16) | (b3 << 24);
#endif
}

// logaddexp in the log2 domain
__device__ __forceinline__ float lg2add(float a, float b) {
  float mx = fmaxf(a, b);
  float d  = fabsf(a - b);
  return mx + flog2(1.0f + fexp2(-d));
}

// ---- kPre: pack x and W into fp8 FRAGMENT-ORDER layouts for 32x32x64 MFMA ----
// Fragment need (mfma_scale_f32_32x32x64_f8f6f4): lane l supplies row/col (l&31),
// k = kb*64 + (l>>5)*32 + [0..32) as 32 contiguous bytes (8 VGPRs).
// Storage: 1 KB slots of 64 lanes x 16 B; lane's 32 B split across two adjacent
// slots (h=0: k+[0,16), h=1: k+[16,32)) so kA staging stays linear 1 KB DMA
// bursts and ds_read_b128 at lane*16 stays conflict-free.
// Xfp slot: tM*32768 + ((kb*2+rt)*2+h)*1024 + l*16
//   = fp8( x[tM*64 + rt*32 + (l&31)][kb*64 + (l>>5)*32 + h*16 + j] ), j=0..15
// Wp  slot: cb*32768 + ((kb*2+ct)*2+h)*1024 + l*16
//   = fp8( 16 * W[cb*64 + ct*32 + (l&31)][kb*64 + (l>>5)*32 + h*16 + j] )
// Thread t <-> output slot t: writes perfectly coalesced (16 B consecutive);
// reads are one 64 B contiguous row-chunk per thread.
__global__ __launch_bounds__(256) void kPre(const float* __restrict__ x,
                                            const float* __restrict__ W,
                                            unsigned char* __restrict__ Xfp,
                                            unsigned char* __restrict__ Wp) {
  const int t = blockIdx.x * 256 + threadIdx.x;
  if (t < 524288) {                     // X part: 8 MB / 16 B = 524288 slots
    const int tM = t >> 11, s = t & 2047;
    const int l = s & 63, h = (s >> 6) & 1, rt = (s >> 7) & 1, kb = s >> 8;
    const int row = tM * 64 + rt * 32 + (l & 31);
    const int col = kb * 64 + ((l >> 5) << 5) + h * 16;
    const float* p = x + (size_t)row * Dd + col;
    uint4 o;
    o.x = cvt4_fp8(*(const float4*)p, 1.0f);
    o.y = cvt4_fp8(*(const float4*)(p + 4), 1.0f);
    o.z = cvt4_fp8(*(const float4*)(p + 8), 1.0f);
    o.w = cvt4_fp8(*(const float4*)(p + 12), 1.0f);
    *(uint4*)(Xfp + (size_t)t * 16) = o;
  } else {                              // W part: 2 MB / 16 B = 131072 slots
    const int tt = t - 524288;
    const int cb = tt >> 11, s = tt & 2047;
    const int l = s & 63, h = (s >> 6) & 1, ct = (s >> 7) & 1, kb = s >> 8;
    const int row = cb * 64 + ct * 32 + (l & 31);
    const int col = kb * 64 + ((l >> 5) << 5) + h * 16;
    const float* p = W + (size_t)row * Dd + col;
    uint4 o;
    o.x = cvt4_fp8(*(const float4*)p, 16.0f);       // x16 prescale into e4m3 range
    o.y = cvt4_fp8(*(const float4*)(p + 4), 16.0f); // (undone by MX scale_b = 2^-4)
    o.z = cvt4_fp8(*(const float4*)(p + 8), 16.0f);
    o.w = cvt4_fp8(*(const float4*)(p + 12), 16.0f);
    *(uint4*)(Wp + (size_t)tt * 16) = o;
  }
}

// ---- barrier-free MX-fp8 GEMM + exp-sum partials + beam scatter, M_tile=64 ----
// grid 4096, 256 threads (4 waves). Block = 64 rows x 256 cols, full K=512.
// mfma_scale_f32_32x32x64_f8f6f4: 32 MFMA/wave (8 k-steps x 2x2 tiles) at the
// MX rate (~4.7 PF ceiling vs 2.1 PF for non-scaled fp8). scale_a = 1.0
// (e8m0 127), scale_b = 2^-4 (e8m0 123) folds away the W x16 prescale, so
// acc holds TRUE logits (no 0.0625 dequant in the epilogues).
// A = 32 KB packed LDS (linear 1KB DMA bursts, conflict-free ds_read_b128);
// B = 4 dwordx4 global loads/k-step, depth-1 prefetch, zero K-loop barriers,
// full unroll.
// REGISTER BUDGET (round-1/2 lesson): working set = 64 acc + 48 frag +
// ~30 addr/temps + scheduler-hoisted loads (zero barriers = unlimited
// hoisting). Cap 128 (256,4): massive spill (WRITE 538 MB, MfmaUtil 7%).
// Cap 170 (256,3): still spilling (WRITE 372 MB, VGPR 84). (256,2) caps
// at 256 -> 100+ regs headroom, spill-impossible; 2 blocks/CU (8 waves)
// still covers the MFMA pipe (4 independent acc chains/wave).
__global__ __launch_bounds__(256, 2) void kA(const unsigned char* __restrict__ Xfp,
                                             const unsigned char* __restrict__ Wp,
                                             const float* __restrict__ bias,
                                             const int* __restrict__ beam,
                                             const int* __restrict__ blankp,
                                             float* __restrict__ Spart,
                                             float* __restrict__ selL,
                                             int CB) {
  __shared__ unsigned char Ald[32768];   // packed A tile (64 rows x 512 K)
  __shared__ float Spw[4][64];
  __shared__ int   selv[31];
  __shared__ float selb[31];

  const int tid = threadIdx.x;
  const int tileN = blockIdx.x & 15;
  const int tileM = blockIdx.x >> 4;
  const int row0 = tileM * 64, col0 = tileN * 256;
  const int bb = row0 >> 9;              // batch of this block (64 | 512)
  const int lane = tid & 63, w = tid >> 6;
  const int l31 = lane & 31, hi = lane >> 5;

  if (tid < 31) {
    int v = (tid == 0) ? *blankp : beam[bb * CB + tid - 1];
    selv[tid] = v;
    selb[tid] = bias[v];
  }

  // stage packed A tile: 32 x 1KB fully-linear DMA bursts (wave w does 8)
  const unsigned char* src = Xfp + (size_t)tileM * 32768;
  #pragma unroll
  for (int i = 0; i < 8; ++i) {
    int off = (w * 8 + i) * 1024;
    __builtin_amdgcn_global_load_lds((const GLOBAL_AS void*)(src + off + lane * 16),
                                     (LDS_AS void*)(Ald + off), 16, 0, 0);
  }
  __syncthreads();                       // only barrier before epilogue

  const int colw = col0 + w * 64;
  const int cb = tileN * 4 + w;

  f32x16 acc[2][2];                      // acc[ct][rt]
  #pragma unroll
  for (int ct = 0; ct < 2; ++ct)
    #pragma unroll
    for (int rt = 0; rt < 2; ++rt)
      #pragma unroll
      for (int r = 0; r < 16; ++r) acc[ct][rt][r] = 0.f;

  const unsigned char* wpB = Wp + (size_t)cb * 32768 + lane * 16;

  i32x8 bc[2];
  #pragma unroll
  for (int ct = 0; ct < 2; ++ct) {
    i32x4 lo = *(const i32x4*)(wpB + (ct * 2) * 1024);
    i32x4 hx = *(const i32x4*)(wpB + (ct * 2 + 1) * 1024);
    bc[ct] = __builtin_shufflevector(lo, hx, 0, 1, 2, 3, 4, 5, 6, 7);
  }

  #pragma unroll
  for (int kb = 0; kb < 8; ++kb) {
    i32x8 af[2];
    #pragma unroll
    for (int rt = 0; rt < 2; ++rt) {     // linear conflict-free b128 pairs
      i32x4 lo = *(const i32x4*)&Ald[(kb * 4 + rt * 2) * 1024 + lane * 16];
      i32x4 hx = *(const i32x4*)&Ald[(kb * 4 + rt * 2 + 1) * 1024 + lane * 16];
      af[rt] = __builtin_shufflevector(lo, hx, 0, 1, 2, 3, 4, 5, 6, 7);
    }
    i32x8 bn[2];
    const int kn = (kb < 7) ? kb + 1 : 7;   // depth-1 B prefetch
    #pragma unroll
    for (int ct = 0; ct < 2; ++ct) {
      i32x4 lo = *(const i32x4*)(wpB + (kn * 4 + ct * 2) * 1024);
      i32x4 hx = *(const i32x4*)(wpB + (kn * 4 + ct * 2 + 1) * 1024);
      bn[ct] = __builtin_shufflevector(lo, hx, 0, 1, 2, 3, 4, 5, 6, 7);
    }
    #pragma unroll
    for (int ct = 0; ct < 2; ++ct)
      #pragma unroll
      for (int rt = 0; rt < 2; ++rt)
        acc[ct][rt] = __builtin_amdgcn_mfma_scale_f32_32x32x64_f8f6f4(
            af[rt], bc[ct], acc[ct][rt],
            0, 0,                         // cbsz=fp8(A), blgp=fp8(B)
            0, 0x7f7f7f7f,                // scale_a = 2^0  (e8m0 127)
            0, 0x7b7b7b7b);               // scale_b = 2^-4 (e8m0 123)
    bc[0] = bn[0]; bc[1] = bn[1];
  }

  // epilogue 1: row-wise sum(exp(logit+bias)) -> per-block partial (no atomics)
  // C layout (32x32): col = ct*32 + l31, row = rt*32 + (reg&3) + 8*(reg>>2) + 4*hi
  float bvl[2];
  #pragma unroll
  for (int ct = 0; ct < 2; ++ct)
    bvl[ct] = bias[colw + ct * 32 + l31] * L2E;

  #pragma unroll
  for (int rt = 0; rt < 2; ++rt) {
    #pragma unroll
    for (int reg = 0; reg < 16; ++reg) {
      float s = fexp2(acc[0][rt][reg] * L2E + bvl[0]) +
                fexp2(acc[1][rt][reg] * L2E + bvl[1]);
      s += __shfl_xor(s, 1, 64);          // reduce over 32 cols (lane bits 0..4;
      s += __shfl_xor(s, 2, 64);          //  hi-bit lanes hold different rows,
      s += __shfl_xor(s, 4, 64);          //  never mixed by this tree)
      s += __shfl_xor(s, 8, 64);
      s += __shfl_xor(s, 16, 64);
      if (l31 == 0)
        Spw[w][rt * 32 + (reg & 3) + 8 * (reg >> 2) + 4 * hi] = s;
    }
  }
  __syncthreads();
  if (tid < 64) {
    float p = Spw[0][tid] + Spw[1][tid] + Spw[2][tid] + Spw[3][tid];
    Spart[(size_t)tileN * BT + row0 + tid] = p;
  }

  // epilogue 2: beam-column scatter (raw ln-domain logit + bias)
  const int tbase = row0 & 511;
  for (int s = 0; s < 31; ++s) {
    int local = selv[s] - colw;
    #pragma unroll
    for (int ct = 0; ct < 2; ++ct) {      // static ct: keeps acc in registers
      if (local >= ct * 32 && local < (ct + 1) * 32 && l31 == (local & 31)) {
        float bvs = selb[s];
        #pragma unroll
        for (int rt = 0; rt < 2; ++rt)
          #pragma unroll
          for (int reg = 0; reg < 16; ++reg) {
            int t = tbase + rt * 32 + (reg & 3) + 8 * (reg >> 2) + 4 * hi;
            selL[((size_t)bb * Tt + t) * 31 + s] = acc[ct][rt][reg] + bvs;
          }
      }
    }
  }
}

// ---- CTC DP + output assembly, log2 domain. grid: B blocks x 256 threads ----
__global__ __launch_bounds__(256) void kC(const float* __restrict__ selL,
                                          const float* __restrict__ Spart,
                                          const int* __restrict__ xl,
                                          const int* __restrict__ beam,
                                          const int* __restrict__ blankp,
                                          const int* __restrict__ eosp,
                                          float* __restrict__ out,
                                          int Ly, int CB) {
  __shared__ float sl[Tt * 31];     // raw logits * log2(e)
  __shared__ float lgS[Tt];         // log2(sum_exp)
  __shared__ float lastP1[Tt];      // log2-domain blank cumsum
  __shared__ float blankLp[Tt];     // log2-domain blank logp
  const int b = blockIdx.x, tid = threadIdx.x;

  for (int i = tid; i < Tt * 31; i += 256)
    sl[i] = selL[(size_t)b * Tt * 31 + i] * L2E;
  for (int tt = tid; tt < Tt; tt += 256) {
    float s = 0.f;
    #pragma unroll
    for (int n = 0; n < 16; ++n) s += Spart[(size_t)n * BT + b * Tt + tt];
    lgS[tt] = flog2(s);
  }
  __syncthreads();

  float* orow = out + (size_t)b * Vv;
  for (int i = tid; i < Vv; i += 256) orow[i] = LOGZERO;

  const int xlb = xl[b];
  float curP = LOGZERO;
  if (tid < 64) {
    const int lane = tid;
    float vloc[8];
    float run = 0.f;
    #pragma unroll
    for (int u = 0; u < 8; ++u) {
      int t = lane * 8 + u;
      float bl = sl[t * 31] - lgS[t];
      blankLp[t] = bl;
      run += bl;
      vloc[u] = run;
    }
    float inc = run;
    #pragma unroll
    for (int off = 1; off < 64; off <<= 1) {
      float o = __shfl_up(inc, off, 64);
      if (lane >= off) inc += o;
    }
    float excl = inc - run;
    #pragma unroll
    for (int u = 0; u < 8; ++u) lastP1[lane * 8 + u] = vloc[u] + excl;

    const int kk = (lane < CB) ? lane : (CB - 1);
    const float LOG2ZERO = LOGZERO * L2E;
    float Pn = LOG2ZERO, Pb = LOG2ZERO;
    float mrun = -3.0e38f, srun = 0.0f;
    int start = (Ly < Tt - 1) ? Ly : (Tt - 1);
    if (start == 0) {
      Pn = sl[1 + kk] - lgS[0];
      float vv = (0 < xlb) ? lg2add(Pn, Pb) : LOG2ZERO;
      float nm = fmaxf(mrun, vv);
      srun = srun * fexp2(mrun - nm) + fexp2(vv - nm);
      mrun = nm;
    }
    int t0 = (start > 1) ? start : 1;
    #pragma unroll 2
    for (int t = t0; t < Tt; ++t) {
      float xn = sl[t * 31 + 1 + kk] - lgS[t];
      float xb = blankLp[t];
      float pref = lastP1[t - 1];   // lastPsum == lastP1 bit-exactly
      float Pn2 = lg2add(Pn, pref) + xn;
      float Pb2 = lg2add(Pn, Pb) + xb;
      Pn = Pn2; Pb = Pb2;
      float vv = (t < xlb) ? lg2add(Pn, Pb) : LOG2ZERO;   // off critical path
      float nm = fmaxf(mrun, vv);
      srun = srun * fexp2(mrun - nm) + fexp2(vv - nm);
      mrun = nm;
    }
    curP = (mrun + flog2(srun)) * LN2;       // back to ln domain
  }
  __syncthreads();   // LOGZERO fill + lastP1 complete

  if (tid < 64) {
    if (tid < CB) orow[beam[b * CB + tid]] = curP;
  }
  __syncthreads();
  if (tid == 0) {
    float eosv = (xlb >= 1) ? lastP1[xlb - 1] * LN2 : 0.0f;
    orow[*eosp] = eosv;
    orow[*blankp] = LOGZERO;
  }
}

extern "C" void kernel_launch(void* const* d_in, const int* in_sizes, int n_in,
                              void* d_out, int out_size, void* d_ws, size_t ws_size,
                              hipStream_t stream) {
  (void)n_in; (void)out_size; (void)ws_size;
  const float* x    = (const float*)d_in[0];
  const float* W    = (const float*)d_in[1];
  const float* bias = (const float*)d_in[2];
  const int* xl     = (const int*)d_in[3];
  const int* beam   = (const int*)d_in[5];
  const int* blankp = (const int*)d_in[6];
  const int* eosp   = (const int*)d_in[7];
  const int Ly = in_sizes[4] / Bb;
  const int CB = in_sizes[5] / Bb;

  float* Spart = (float*)d_ws;                                            // 1 MB
  float* selL  = (float*)((char*)d_ws + (size_t)0x100000);                // 2.03 MB
  unsigned char* Xfp = (unsigned char*)((char*)d_ws + (size_t)0x400000);  // 8 MB
  unsigned char* Wp  = (unsigned char*)((char*)d_ws + (size_t)0xC00000);  // 2 MB
  float* outf = (float*)d_out;

  kPre<<<2560, 256, 0, stream>>>(x, W, Xfp, Wp);
  kA<<<4096, 256, 0, stream>>>(Xfp, Wp, bias, beam, blankp, Spart, selL, CB);
  kC<<<Bb, 256, 0, stream>>>(selL, Spart, xl, beam, blankp, eosp, outf, Ly, CB);
}

// Round 4
// 226.271 us; speedup vs baseline: 1.4362x; 1.1226x over previous
//
#include <hip/hip_runtime.h>
#include <hip/hip_fp8.h>

#define LOGZERO -4290774016.0f   // -(65504^2), exactly representable in fp32
#define L2E 1.4426950408889634f  // log2(e)
#define LN2 0.6931471805599453f

constexpr int Bb = 32, Tt = 512, Dd = 512, Vv = 4096;
constexpr int BT = Bb * Tt;

typedef __attribute__((ext_vector_type(4)))  float f32x4;
typedef __attribute__((ext_vector_type(16))) float f32x16;
typedef __attribute__((ext_vector_type(4)))  int   i32x4;
typedef __attribute__((ext_vector_type(8)))  int   i32x8;

#define GLOBAL_AS __attribute__((address_space(1)))
#define LDS_AS    __attribute__((address_space(3)))

__device__ __forceinline__ float fexp2(float x) { return __builtin_amdgcn_exp2f(x); }  // 2^x
__device__ __forceinline__ float flog2(float x) { return __builtin_amdgcn_logf(x); }   // log2(x)

// pack 4 floats (scaled) -> 4 OCP e4m3 bytes
__device__ __forceinline__ unsigned cvt4_fp8(float4 v, float s) {
#if __has_builtin(__builtin_amdgcn_cvt_pk_fp8_f32)
  int p = __builtin_amdgcn_cvt_pk_fp8_f32(v.x * s, v.y * s, 0, false);
  p = __builtin_amdgcn_cvt_pk_fp8_f32(v.z * s, v.w * s, p, true);
  return (unsigned)p;
#else
  unsigned b0 = __hip_cvt_float_to_fp8(v.x * s, __HIP_SATFINITE, __HIP_E4M3);
  unsigned b1 = __hip_cvt_float_to_fp8(v.y * s, __HIP_SATFINITE, __HIP_E4M3);
  unsigned b2 = __hip_cvt_float_to_fp8(v.z * s, __HIP_SATFINITE, __HIP_E4M3);
  unsigned b3 = __hip_cvt_float_to_fp8(v.w * s, __HIP_SATFINITE, __HIP_E4M3);
  return b0 | (b1 << 8) | (b2 << 16) | (b3 << 24);
#endif
}

// logaddexp in the log2 domain
__device__ __forceinline__ float lg2add(float a, float b) {
  float mx = fmaxf(a, b);
  float d  = fabsf(a - b);
  return mx + flog2(1.0f + fexp2(-d));
}

// ---- kPre: pack x and W into fp8 FRAGMENT-ORDER layouts for 32x32x64 MFMA ----
// Fragment need (mfma_scale_f32_32x32x64_f8f6f4): lane l supplies row/col (l&31),
// k = kb*64 + (l>>5)*32 + [0..32) as 32 contiguous bytes (8 VGPRs).
// Storage: 1 KB slots of 64 lanes x 16 B; lane's 32 B split across two adjacent
// slots (h=0: k+[0,16), h=1: k+[16,32)) so kA staging stays linear 1 KB DMA
// bursts and ds_read_b128 at lane*16 stays conflict-free.
// Xfp (32-ROW tiles now, 16 KB each): slot = tM*1024 + (kb*2+h)*1024/16... i.e.
//   slot16 = tM*1024 + (kb*2+h)*64 + l
//   = fp8( x[tM*32 + (l&31)][kb*64 + (l>>5)*32 + h*16 + j] ), j=0..15
// Wp  (UNCHANGED from round 3): slot16 = cb*2048 + (kb*4 + ct*2 + h)*64 + l
//   = fp8( 16 * W[cb*64 + ct*32 + (l&31)][kb*64 + (l>>5)*32 + h*16 + j] )
// Thread t <-> output slot t: writes perfectly coalesced (16 B consecutive);
// reads are one 64 B contiguous row-chunk per thread.
__global__ __launch_bounds__(256) void kPre(const float* __restrict__ x,
                                            const float* __restrict__ W,
                                            unsigned char* __restrict__ Xfp,
                                            unsigned char* __restrict__ Wp) {
  const int t = blockIdx.x * 256 + threadIdx.x;
  if (t < 524288) {                     // X part: 8 MB / 16 B = 524288 slots
    const int tM = t >> 10, s = t & 1023;       // tM = 0..511 (32-row tiles)
    const int l = s & 63, h = (s >> 6) & 1, kb = s >> 7;   // kb = 0..7
    const int row = tM * 32 + (l & 31);
    const int col = kb * 64 + ((l >> 5) << 5) + h * 16;
    const float* p = x + (size_t)row * Dd + col;
    uint4 o;
    o.x = cvt4_fp8(*(const float4*)p, 1.0f);
    o.y = cvt4_fp8(*(const float4*)(p + 4), 1.0f);
    o.z = cvt4_fp8(*(const float4*)(p + 8), 1.0f);
    o.w = cvt4_fp8(*(const float4*)(p + 12), 1.0f);
    *(uint4*)(Xfp + (size_t)t * 16) = o;
  } else {                              // W part: 2 MB / 16 B = 131072 slots
    const int tt = t - 524288;
    const int cb = tt >> 11, s = tt & 2047;
    const int l = s & 63, h = (s >> 6) & 1, ct = (s >> 7) & 1, kb = s >> 8;
    const int row = cb * 64 + ct * 32 + (l & 31);
    const int col = kb * 64 + ((l >> 5) << 5) + h * 16;
    const float* p = W + (size_t)row * Dd + col;
    uint4 o;
    o.x = cvt4_fp8(*(const float4*)p, 16.0f);       // x16 prescale into e4m3 range
    o.y = cvt4_fp8(*(const float4*)(p + 4), 16.0f); // (undone by MX scale_b = 2^-4)
    o.z = cvt4_fp8(*(const float4*)(p + 8), 16.0f);
    o.w = cvt4_fp8(*(const float4*)(p + 12), 16.0f);
    *(uint4*)(Wp + (size_t)tt * 16) = o;
  }
}

// ---- barrier-free MX-fp8 GEMM + exp-sum partials + beam scatter, M_tile=32 ----
// grid 8192, 256 threads (4 waves). Block = 32 rows x 256 cols, full K=512.
// ROUND-3 LESSON: total time = per-block latency (~15 us, MFMA-type-invariant)
// x (4096 tiles / resident blocks). The lever is RESIDENT BLOCKS, not per-wave
// instruction count. 64-row blocks need acc=64 regs/thread -> ~150-reg working
// set -> can't fit 4 blocks/CU (128-reg cap) without spill (rounds 1-2).
// 32-row blocks: per-wave output 32x64 -> acc 32 + af 8 + bc 16 + bn 16 +
// ~25 temps ~ 95 regs -> fits 128 cap with slack -> 4 blocks/CU, 16 waves.
// LDS 17 KB. Cost: B L2 traffic doubles (1 GB total, ~30 TB/s < 34.5 ceiling).
// mfma_scale_f32_32x32x64_f8f6f4, 16 MFMA/wave (8 k-steps x 2 col-tiles).
// scale_a = 2^0 (e8m0 127), scale_b = 2^-4 (123) undoes the W x16 prescale.
__global__ __launch_bounds__(256, 4) void kA(const unsigned char* __restrict__ Xfp,
                                             const unsigned char* __restrict__ Wp,
                                             const float* __restrict__ bias,
                                             const int* __restrict__ beam,
                                             const int* __restrict__ blankp,
                                             float* __restrict__ Spart,
                                             float* __restrict__ selL,
                                             int CB) {
  __shared__ unsigned char Ald[16384];   // packed A tile (32 rows x 512 K)
  __shared__ float Spw[4][32];
  __shared__ int   selv[31];
  __shared__ float selb[31];

  const int tid = threadIdx.x;
  const int tileN = blockIdx.x & 15;
  const int tileM = blockIdx.x >> 4;     // 0..511 (32-row tiles)
  const int row0 = tileM * 32, col0 = tileN * 256;
  const int bb = row0 >> 9;              // batch of this block (32 | 512)
  const int lane = tid & 63, w = tid >> 6;
  const int l31 = lane & 31, hi = lane >> 5;

  if (tid < 31) {
    int v = (tid == 0) ? *blankp : beam[bb * CB + tid - 1];
    selv[tid] = v;
    selb[tid] = bias[v];
  }

  // stage packed A tile: 16 x 1KB fully-linear DMA bursts (wave w does 4)
  const unsigned char* src = Xfp + (size_t)tileM * 16384;
  #pragma unroll
  for (int i = 0; i < 4; ++i) {
    int off = (w * 4 + i) * 1024;
    __builtin_amdgcn_global_load_lds((const GLOBAL_AS void*)(src + off + lane * 16),
                                     (LDS_AS void*)(Ald + off), 16, 0, 0);
  }
  __syncthreads();                       // only barrier before epilogue

  const int colw = col0 + w * 64;
  const int cb = tileN * 4 + w;

  f32x16 acc[2];                         // acc[ct], 32x32 each
  #pragma unroll
  for (int ct = 0; ct < 2; ++ct)
    #pragma unroll
    for (int r = 0; r < 16; ++r) acc[ct][r] = 0.f;

  const unsigned char* wpB = Wp + (size_t)cb * 32768 + lane * 16;

  i32x8 bc[2];
  #pragma unroll
  for (int ct = 0; ct < 2; ++ct) {
    i32x4 lo = *(const i32x4*)(wpB + (ct * 2) * 1024);
    i32x4 hx = *(const i32x4*)(wpB + (ct * 2 + 1) * 1024);
    bc[ct] = __builtin_shufflevector(lo, hx, 0, 1, 2, 3, 4, 5, 6, 7);
  }

  #pragma unroll
  for (int kb = 0; kb < 8; ++kb) {
    i32x8 af;
    {                                    // linear conflict-free b128 pair
      i32x4 lo = *(const i32x4*)&Ald[(kb * 2) * 1024 + lane * 16];
      i32x4 hx = *(const i32x4*)&Ald[(kb * 2 + 1) * 1024 + lane * 16];
      af = __builtin_shufflevector(lo, hx, 0, 1, 2, 3, 4, 5, 6, 7);
    }
    i32x8 bn[2];
    const int kn = (kb < 7) ? kb + 1 : 7;   // depth-1 B prefetch
    #pragma unroll
    for (int ct = 0; ct < 2; ++ct) {
      i32x4 lo = *(const i32x4*)(wpB + (kn * 4 + ct * 2) * 1024);
      i32x4 hx = *(const i32x4*)(wpB + (kn * 4 + ct * 2 + 1) * 1024);
      bn[ct] = __builtin_shufflevector(lo, hx, 0, 1, 2, 3, 4, 5, 6, 7);
    }
    #pragma unroll
    for (int ct = 0; ct < 2; ++ct)
      acc[ct] = __builtin_amdgcn_mfma_scale_f32_32x32x64_f8f6f4(
          af, bc[ct], acc[ct],
          0, 0,                           // cbsz=fp8(A), blgp=fp8(B)
          0, 0x7f7f7f7f,                  // scale_a = 2^0  (e8m0 127)
          0, 0x7b7b7b7b);                 // scale_b = 2^-4 (e8m0 123)
    bc[0] = bn[0]; bc[1] = bn[1];
  }

  // epilogue 1: row-wise sum(exp(logit+bias)) -> per-block partial (no atomics)
  // C layout (32x32): col = ct*32 + l31, row = (reg&3) + 8*(reg>>2) + 4*hi
  float bvl[2];
  #pragma unroll
  for (int ct = 0; ct < 2; ++ct)
    bvl[ct] = bias[colw + ct * 32 + l31] * L2E;

  #pragma unroll
  for (int reg = 0; reg < 16; ++reg) {
    float s = fexp2(acc[0][reg] * L2E + bvl[0]) +
              fexp2(acc[1][reg] * L2E + bvl[1]);
    s += __shfl_xor(s, 1, 64);            // reduce over 32 cols (lane bits 0..4;
    s += __shfl_xor(s, 2, 64);            //  hi-bit lanes hold different rows,
    s += __shfl_xor(s, 4, 64);            //  never mixed by this tree)
    s += __shfl_xor(s, 8, 64);
    s += __shfl_xor(s, 16, 64);
    if (l31 == 0)
      Spw[w][(reg & 3) + 8 * (reg >> 2) + 4 * hi] = s;
  }
  __syncthreads();
  if (tid < 32) {
    float p = Spw[0][tid] + Spw[1][tid] + Spw[2][tid] + Spw[3][tid];
    Spart[(size_t)tileN * BT + row0 + tid] = p;
  }

  // epilogue 2: beam-column scatter (raw ln-domain logit + bias)
  const int tbase = row0 & 511;
  for (int s = 0; s < 31; ++s) {
    int local = selv[s] - colw;
    #pragma unroll
    for (int ct = 0; ct < 2; ++ct) {      // static ct: keeps acc in registers
      if (local >= ct * 32 && local < (ct + 1) * 32 && l31 == (local & 31)) {
        float bvs = selb[s];
        #pragma unroll
        for (int reg = 0; reg < 16; ++reg) {
          int t = tbase + (reg & 3) + 8 * (reg >> 2) + 4 * hi;
          selL[((size_t)bb * Tt + t) * 31 + s] = acc[ct][reg] + bvs;
        }
      }
    }
  }
}

// ---- CTC DP + output assembly, log2 domain. grid: B blocks x 256 threads ----
__global__ __launch_bounds__(256) void kC(const float* __restrict__ selL,
                                          const float* __restrict__ Spart,
                                          const int* __restrict__ xl,
                                          const int* __restrict__ beam,
                                          const int* __restrict__ blankp,
                                          const int* __restrict__ eosp,
                                          float* __restrict__ out,
                                          int Ly, int CB) {
  __shared__ float sl[Tt * 31];     // raw logits * log2(e)
  __shared__ float lgS[Tt];         // log2(sum_exp)
  __shared__ float lastP1[Tt];      // log2-domain blank cumsum
  __shared__ float blankLp[Tt];     // log2-domain blank logp
  const int b = blockIdx.x, tid = threadIdx.x;

  for (int i = tid; i < Tt * 31; i += 256)
    sl[i] = selL[(size_t)b * Tt * 31 + i] * L2E;
  for (int tt = tid; tt < Tt; tt += 256) {
    float s = 0.f;
    #pragma unroll
    for (int n = 0; n < 16; ++n) s += Spart[(size_t)n * BT + b * Tt + tt];
    lgS[tt] = flog2(s);
  }
  __syncthreads();

  float* orow = out + (size_t)b * Vv;
  for (int i = tid; i < Vv; i += 256) orow[i] = LOGZERO;

  const int xlb = xl[b];
  float curP = LOGZERO;
  if (tid < 64) {
    const int lane = tid;
    float vloc[8];
    float run = 0.f;
    #pragma unroll
    for (int u = 0; u < 8; ++u) {
      int t = lane * 8 + u;
      float bl = sl[t * 31] - lgS[t];
      blankLp[t] = bl;
      run += bl;
      vloc[u] = run;
    }
    float inc = run;
    #pragma unroll
    for (int off = 1; off < 64; off <<= 1) {
      float o = __shfl_up(inc, off, 64);
      if (lane >= off) inc += o;
    }
    float excl = inc - run;
    #pragma unroll
    for (int u = 0; u < 8; ++u) lastP1[lane * 8 + u] = vloc[u] + excl;

    const int kk = (lane < CB) ? lane : (CB - 1);
    const float LOG2ZERO = LOGZERO * L2E;
    float Pn = LOG2ZERO, Pb = LOG2ZERO;
    float mrun = -3.0e38f, srun = 0.0f;
    int start = (Ly < Tt - 1) ? Ly : (Tt - 1);
    if (start == 0) {
      Pn = sl[1 + kk] - lgS[0];
      float vv = (0 < xlb) ? lg2add(Pn, Pb) : LOG2ZERO;
      float nm = fmaxf(mrun, vv);
      srun = srun * fexp2(mrun - nm) + fexp2(vv - nm);
      mrun = nm;
    }
    int t0 = (start > 1) ? start : 1;
    #pragma unroll 2
    for (int t = t0; t < Tt; ++t) {
      float xn = sl[t * 31 + 1 + kk] - lgS[t];
      float xb = blankLp[t];
      float pref = lastP1[t - 1];   // lastPsum == lastP1 bit-exactly
      float Pn2 = lg2add(Pn, pref) + xn;
      float Pb2 = lg2add(Pn, Pb) + xb;
      Pn = Pn2; Pb = Pb2;
      float vv = (t < xlb) ? lg2add(Pn, Pb) : LOG2ZERO;   // off critical path
      float nm = fmaxf(mrun, vv);
      srun = srun * fexp2(mrun - nm) + fexp2(vv - nm);
      mrun = nm;
    }
    curP = (mrun + flog2(srun)) * LN2;       // back to ln domain
  }
  __syncthreads();   // LOGZERO fill + lastP1 complete

  if (tid < 64) {
    if (tid < CB) orow[beam[b * CB + tid]] = curP;
  }
  __syncthreads();
  if (tid == 0) {
    float eosv = (xlb >= 1) ? lastP1[xlb - 1] * LN2 : 0.0f;
    orow[*eosp] = eosv;
    orow[*blankp] = LOGZERO;
  }
}

extern "C" void kernel_launch(void* const* d_in, const int* in_sizes, int n_in,
                              void* d_out, int out_size, void* d_ws, size_t ws_size,
                              hipStream_t stream) {
  (void)n_in; (void)out_size; (void)ws_size;
  const float* x    = (const float*)d_in[0];
  const float* W    = (const float*)d_in[1];
  const float* bias = (const float*)d_in[2];
  const int* xl     = (const int*)d_in[3];
  const int* beam   = (const int*)d_in[5];
  const int* blankp = (const int*)d_in[6];
  const int* eosp   = (const int*)d_in[7];
  const int Ly = in_sizes[4] / Bb;
  const int CB = in_sizes[5] / Bb;

  float* Spart = (float*)d_ws;                                            // 1 MB
  float* selL  = (float*)((char*)d_ws + (size_t)0x100000);                // 2.03 MB
  unsigned char* Xfp = (unsigned char*)((char*)d_ws + (size_t)0x400000);  // 8 MB
  unsigned char* Wp  = (unsigned char*)((char*)d_ws + (size_t)0xC00000);  // 2 MB
  float* outf = (float*)d_out;

  kPre<<<2560, 256, 0, stream>>>(x, W, Xfp, Wp);
  kA<<<8192, 256, 0, stream>>>(Xfp, Wp, bias, beam, blankp, Spart, selL, CB);
  kC<<<Bb, 256, 0, stream>>>(selL, Spart, xl, beam, blankp, eosp, outf, Ly, CB);
}

// Round 5
// 221.893 us; speedup vs baseline: 1.4646x; 1.0197x over previous
//
#include <hip/hip_runtime.h>
#include <hip/hip_fp8.h>

#define LOGZERO -4290774016.0f   // -(65504^2), exactly representable in fp32
#define L2E 1.4426950408889634f  // log2(e)
#define LN2 0.6931471805599453f

constexpr int Bb = 32, Tt = 512, Dd = 512, Vv = 4096;
constexpr int BT = Bb * Tt;

typedef __attribute__((ext_vector_type(4)))  float f32x4;
typedef __attribute__((ext_vector_type(16))) float f32x16;
typedef __attribute__((ext_vector_type(4)))  int   i32x4;
typedef __attribute__((ext_vector_type(8)))  int   i32x8;

#define GLOBAL_AS __attribute__((address_space(1)))
#define LDS_AS    __attribute__((address_space(3)))

__device__ __forceinline__ float fexp2(float x) { return __builtin_amdgcn_exp2f(x); }  // 2^x
__device__ __forceinline__ float flog2(float x) { return __builtin_amdgcn_logf(x); }   // log2(x)

// pack 4 floats (scaled) -> 4 OCP e4m3 bytes
__device__ __forceinline__ unsigned cvt4_fp8(float4 v, float s) {
#if __has_builtin(__builtin_amdgcn_cvt_pk_fp8_f32)
  int p = __builtin_amdgcn_cvt_pk_fp8_f32(v.x * s, v.y * s, 0, false);
  p = __builtin_amdgcn_cvt_pk_fp8_f32(v.z * s, v.w * s, p, true);
  return (unsigned)p;
#else
  unsigned b0 = __hip_cvt_float_to_fp8(v.x * s, __HIP_SATFINITE, __HIP_E4M3);
  unsigned b1 = __hip_cvt_float_to_fp8(v.y * s, __HIP_SATFINITE, __HIP_E4M3);
  unsigned b2 = __hip_cvt_float_to_fp8(v.z * s, __HIP_SATFINITE, __HIP_E4M3);
  unsigned b3 = __hip_cvt_float_to_fp8(v.w * s, __HIP_SATFINITE, __HIP_E4M3);
  return b0 | (b1 << 8) | (b2 << 16) | (b3 << 24);
#endif
}

// logaddexp in the log2 domain
__device__ __forceinline__ float lg2add(float a, float b) {
  float mx = fmaxf(a, b);
  float d  = fabsf(a - b);
  return mx + flog2(1.0f + fexp2(-d));
}

// ---- kPre: pack x and W into fp8 FRAGMENT-ORDER layouts for 32x32x64 MFMA ----
// Fragment need (mfma_scale_f32_32x32x64_f8f6f4): lane l supplies row/col (l&31),
// k = kb*64 + (l>>5)*32 + [0..32) as 32 contiguous bytes (8 VGPRs).
// Storage: 1 KB slots of 64 lanes x 16 B; lane's 32 B split across two adjacent
// slots (h=0: k+[0,16), h=1: k+[16,32)) so kA staging stays linear 1 KB DMA
// bursts and ds_read_b128 at lane*16 stays conflict-free.
// Xfp (32-row tiles, 16 KB each): slot16 = tM*1024 + (kb*2+h)*64 + l
//   = fp8( x[tM*32 + (l&31)][kb*64 + (l>>5)*32 + h*16 + j] ), j=0..15
// Wp: slot16 = cb*2048 + (kb*4 + ct*2 + h)*64 + l
//   = fp8( 16 * W[cb*64 + ct*32 + (l&31)][kb*64 + (l>>5)*32 + h*16 + j] )
// Thread t <-> output slot t: writes perfectly coalesced (16 B consecutive);
// reads are one 64 B contiguous row-chunk per thread.
__global__ __launch_bounds__(256) void kPre(const float* __restrict__ x,
                                            const float* __restrict__ W,
                                            unsigned char* __restrict__ Xfp,
                                            unsigned char* __restrict__ Wp) {
  const int t = blockIdx.x * 256 + threadIdx.x;
  if (t < 524288) {                     // X part: 8 MB / 16 B = 524288 slots
    const int tM = t >> 10, s = t & 1023;       // tM = 0..511 (32-row tiles)
    const int l = s & 63, h = (s >> 6) & 1, kb = s >> 7;   // kb = 0..7
    const int row = tM * 32 + (l & 31);
    const int col = kb * 64 + ((l >> 5) << 5) + h * 16;
    const float* p = x + (size_t)row * Dd + col;
    uint4 o;
    o.x = cvt4_fp8(*(const float4*)p, 1.0f);
    o.y = cvt4_fp8(*(const float4*)(p + 4), 1.0f);
    o.z = cvt4_fp8(*(const float4*)(p + 8), 1.0f);
    o.w = cvt4_fp8(*(const float4*)(p + 12), 1.0f);
    *(uint4*)(Xfp + (size_t)t * 16) = o;
  } else {                              // W part: 2 MB / 16 B = 131072 slots
    const int tt = t - 524288;
    const int cb = tt >> 11, s = tt & 2047;
    const int l = s & 63, h = (s >> 6) & 1, ct = (s >> 7) & 1, kb = s >> 8;
    const int row = cb * 64 + ct * 32 + (l & 31);
    const int col = kb * 64 + ((l >> 5) << 5) + h * 16;
    const float* p = W + (size_t)row * Dd + col;
    uint4 o;
    o.x = cvt4_fp8(*(const float4*)p, 16.0f);       // x16 prescale into e4m3 range
    o.y = cvt4_fp8(*(const float4*)(p + 4), 16.0f); // (undone by MX scale_b = 2^-4)
    o.z = cvt4_fp8(*(const float4*)(p + 8), 16.0f);
    o.w = cvt4_fp8(*(const float4*)(p + 12), 16.0f);
    *(uint4*)(Wp + (size_t)tt * 16) = o;
  }
}

// ---- barrier-free MX-fp8 GEMM + exp-sum partials + beam scatter, M_tile=32 ----
// grid 8192, 256 threads (4 waves). Block = 32 rows x 256 cols, full K=512.
// ROUND-4 LESSONS: (a) concurrency is the lever (4 blk/CU -> 92.9 us), and it
// saturates sublinearly -> take 6 blk/CU: 44 VGPR + 32 AGPR = 76 <= 512/6=85
// cap, LDS 6x17KB = 102KB <= 160. (b) VALUBusy 42% = 39 us, dominated by the
// beam scatter issuing 992 predicated stores/wave for ~2 real hits. The outer
// range test is WAVE-UNIFORM -> readfirstlane + scalar branch skips ~29/31
// beams entirely (s_cbranch, zero VALU).
// mfma_scale_f32_32x32x64_f8f6f4, 16 MFMA/wave (8 k-steps x 2 col-tiles).
// scale_a = 2^0 (e8m0 127), scale_b = 2^-4 (123) undoes the W x16 prescale.
__global__ __launch_bounds__(256, 6) void kA(const unsigned char* __restrict__ Xfp,
                                             const unsigned char* __restrict__ Wp,
                                             const float* __restrict__ bias,
                                             const int* __restrict__ beam,
                                             const int* __restrict__ blankp,
                                             float* __restrict__ Spart,
                                             float* __restrict__ selL,
                                             int CB) {
  __shared__ unsigned char Ald[16384];   // packed A tile (32 rows x 512 K)
  __shared__ float Spw[4][32];
  __shared__ int   selv[31];
  __shared__ float selb[31];

  const int tid = threadIdx.x;
  const int tileN = blockIdx.x & 15;
  const int tileM = blockIdx.x >> 4;     // 0..511 (32-row tiles)
  const int row0 = tileM * 32, col0 = tileN * 256;
  const int bb = row0 >> 9;              // batch of this block (32 | 512)
  const int lane = tid & 63, w = tid >> 6;
  const int l31 = lane & 31, hi = lane >> 5;

  if (tid < 31) {
    int v = (tid == 0) ? *blankp : beam[bb * CB + tid - 1];
    selv[tid] = v;
    selb[tid] = bias[v];
  }

  // stage packed A tile: 16 x 1KB fully-linear DMA bursts (wave w does 4)
  const unsigned char* src = Xfp + (size_t)tileM * 16384;
  #pragma unroll
  for (int i = 0; i < 4; ++i) {
    int off = (w * 4 + i) * 1024;
    __builtin_amdgcn_global_load_lds((const GLOBAL_AS void*)(src + off + lane * 16),
                                     (LDS_AS void*)(Ald + off), 16, 0, 0);
  }
  __syncthreads();                       // only barrier before epilogue

  const int colw = col0 + w * 64;
  const int cb = tileN * 4 + w;

  f32x16 acc[2];                         // acc[ct], 32x32 each
  #pragma unroll
  for (int ct = 0; ct < 2; ++ct)
    #pragma unroll
    for (int r = 0; r < 16; ++r) acc[ct][r] = 0.f;

  const unsigned char* wpB = Wp + (size_t)cb * 32768 + lane * 16;

  i32x8 bc[2];
  #pragma unroll
  for (int ct = 0; ct < 2; ++ct) {
    i32x4 lo = *(const i32x4*)(wpB + (ct * 2) * 1024);
    i32x4 hx = *(const i32x4*)(wpB + (ct * 2 + 1) * 1024);
    bc[ct] = __builtin_shufflevector(lo, hx, 0, 1, 2, 3, 4, 5, 6, 7);
  }

  #pragma unroll
  for (int kb = 0; kb < 8; ++kb) {
    i32x8 af;
    {                                    // linear conflict-free b128 pair
      i32x4 lo = *(const i32x4*)&Ald[(kb * 2) * 1024 + lane * 16];
      i32x4 hx = *(const i32x4*)&Ald[(kb * 2 + 1) * 1024 + lane * 16];
      af = __builtin_shufflevector(lo, hx, 0, 1, 2, 3, 4, 5, 6, 7);
    }
    i32x8 bn[2];
    const int kn = (kb < 7) ? kb + 1 : 7;   // depth-1 B prefetch
    #pragma unroll
    for (int ct = 0; ct < 2; ++ct) {
      i32x4 lo = *(const i32x4*)(wpB + (kn * 4 + ct * 2) * 1024);
      i32x4 hx = *(const i32x4*)(wpB + (kn * 4 + ct * 2 + 1) * 1024);
      bn[ct] = __builtin_shufflevector(lo, hx, 0, 1, 2, 3, 4, 5, 6, 7);
    }
    #pragma unroll
    for (int ct = 0; ct < 2; ++ct)
      acc[ct] = __builtin_amdgcn_mfma_scale_f32_32x32x64_f8f6f4(
          af, bc[ct], acc[ct],
          0, 0,                           // cbsz=fp8(A), blgp=fp8(B)
          0, 0x7f7f7f7f,                  // scale_a = 2^0  (e8m0 127)
          0, 0x7b7b7b7b);                 // scale_b = 2^-4 (e8m0 123)
    bc[0] = bn[0]; bc[1] = bn[1];
  }

  // epilogue 1: row-wise sum(exp(logit+bias)) -> per-block partial (no atomics)
  // C layout (32x32): col = ct*32 + l31, row = (reg&3) + 8*(reg>>2) + 4*hi
  float bvl[2];
  #pragma unroll
  for (int ct = 0; ct < 2; ++ct)
    bvl[ct] = bias[colw + ct * 32 + l31] * L2E;

  #pragma unroll
  for (int reg = 0; reg < 16; ++reg) {
    float s = fexp2(acc[0][reg] * L2E + bvl[0]) +
              fexp2(acc[1][reg] * L2E + bvl[1]);
    s += __shfl_xor(s, 1, 64);            // reduce over 32 cols (lane bits 0..4;
    s += __shfl_xor(s, 2, 64);            //  hi-bit lanes hold different rows,
    s += __shfl_xor(s, 4, 64);            //  never mixed by this tree)
    s += __shfl_xor(s, 8, 64);
    s += __shfl_xor(s, 16, 64);
    if (l31 == 0)
      Spw[w][(reg & 3) + 8 * (reg >> 2) + 4 * hi] = s;
  }
  __syncthreads();
  if (tid < 32) {
    float p = Spw[0][tid] + Spw[1][tid] + Spw[2][tid] + Spw[3][tid];
    Spart[(size_t)tileN * BT + row0 + tid] = p;
  }

  // epilogue 2: beam-column scatter (raw ln-domain logit + bias).
  // selv[s] and colw are wave-uniform -> readfirstlane forces the range
  // test into SGPR/s_cbranch; only the ~2 beams inside this block's 64-col
  // wave window execute any VALU/stores. ct kept static (no runtime acc idx).
  const int tbase = row0 & 511;
  #pragma unroll 1
  for (int s = 0; s < 31; ++s) {
    const int vsel = __builtin_amdgcn_readfirstlane(selv[s]);
    const int local = vsel - colw;
    if (local >= 0 && local < 32) {       // scalar branch, ct = 0
      const float bvs = selb[s];
      if (l31 == local) {
        #pragma unroll
        for (int reg = 0; reg < 16; ++reg) {
          int t = tbase + (reg & 3) + 8 * (reg >> 2) + 4 * hi;
          selL[((size_t)bb * Tt + t) * 31 + s] = acc[0][reg] + bvs;
        }
      }
    } else if (local >= 32 && local < 64) {  // scalar branch, ct = 1
      const float bvs = selb[s];
      if (l31 == (local & 31)) {
        #pragma unroll
        for (int reg = 0; reg < 16; ++reg) {
          int t = tbase + (reg & 3) + 8 * (reg >> 2) + 4 * hi;
          selL[((size_t)bb * Tt + t) * 31 + s] = acc[1][reg] + bvs;
        }
      }
    }
  }
}

// ---- CTC DP + output assembly, log2 domain. grid: B blocks x 256 threads ----
__global__ __launch_bounds__(256) void kC(const float* __restrict__ selL,
                                          const float* __restrict__ Spart,
                                          const int* __restrict__ xl,
                                          const int* __restrict__ beam,
                                          const int* __restrict__ blankp,
                                          const int* __restrict__ eosp,
                                          float* __restrict__ out,
                                          int Ly, int CB) {
  __shared__ float sl[Tt * 31];     // raw logits * log2(e)
  __shared__ float lgS[Tt];         // log2(sum_exp)
  __shared__ float lastP1[Tt];      // log2-domain blank cumsum
  __shared__ float blankLp[Tt];     // log2-domain blank logp
  const int b = blockIdx.x, tid = threadIdx.x;

  for (int i = tid; i < Tt * 31; i += 256)
    sl[i] = selL[(size_t)b * Tt * 31 + i] * L2E;
  for (int tt = tid; tt < Tt; tt += 256) {
    float s = 0.f;
    #pragma unroll
    for (int n = 0; n < 16; ++n) s += Spart[(size_t)n * BT + b * Tt + tt];
    lgS[tt] = flog2(s);
  }
  __syncthreads();

  float* orow = out + (size_t)b * Vv;
  for (int i = tid; i < Vv; i += 256) orow[i] = LOGZERO;

  const int xlb = xl[b];
  float curP = LOGZERO;
  if (tid < 64) {
    const int lane = tid;
    float vloc[8];
    float run = 0.f;
    #pragma unroll
    for (int u = 0; u < 8; ++u) {
      int t = lane * 8 + u;
      float bl = sl[t * 31] - lgS[t];
      blankLp[t] = bl;
      run += bl;
      vloc[u] = run;
    }
    float inc = run;
    #pragma unroll
    for (int off = 1; off < 64; off <<= 1) {
      float o = __shfl_up(inc, off, 64);
      if (lane >= off) inc += o;
    }
    float excl = inc - run;
    #pragma unroll
    for (int u = 0; u < 8; ++u) lastP1[lane * 8 + u] = vloc[u] + excl;

    const int kk = (lane < CB) ? lane : (CB - 1);
    const float LOG2ZERO = LOGZERO * L2E;
    float Pn = LOG2ZERO, Pb = LOG2ZERO;
    float mrun = -3.0e38f, srun = 0.0f;
    int start = (Ly < Tt - 1) ? Ly : (Tt - 1);
    if (start == 0) {
      Pn = sl[1 + kk] - lgS[0];
      float vv = (0 < xlb) ? lg2add(Pn, Pb) : LOG2ZERO;
      float nm = fmaxf(mrun, vv);
      srun = srun * fexp2(mrun - nm) + fexp2(vv - nm);
      mrun = nm;
    }
    int t0 = (start > 1) ? start : 1;
    #pragma unroll 2
    for (int t = t0; t < Tt; ++t) {
      float xn = sl[t * 31 + 1 + kk] - lgS[t];
      float xb = blankLp[t];
      float pref = lastP1[t - 1];   // lastPsum == lastP1 bit-exactly
      float Pn2 = lg2add(Pn, pref) + xn;
      float Pb2 = lg2add(Pn, Pb) + xb;
      Pn = Pn2; Pb = Pb2;
      float vv = (t < xlb) ? lg2add(Pn, Pb) : LOG2ZERO;   // off critical path
      float nm = fmaxf(mrun, vv);
      srun = srun * fexp2(mrun - nm) + fexp2(vv - nm);
      mrun = nm;
    }
    curP = (mrun + flog2(srun)) * LN2;       // back to ln domain
  }
  __syncthreads();   // LOGZERO fill + lastP1 complete

  if (tid < 64) {
    if (tid < CB) orow[beam[b * CB + tid]] = curP;
  }
  __syncthreads();
  if (tid == 0) {
    float eosv = (xlb >= 1) ? lastP1[xlb - 1] * LN2 : 0.0f;
    orow[*eosp] = eosv;
    orow[*blankp] = LOGZERO;
  }
}

extern "C" void kernel_launch(void* const* d_in, const int* in_sizes, int n_in,
                              void* d_out, int out_size, void* d_ws, size_t ws_size,
                              hipStream_t stream) {
  (void)n_in; (void)out_size; (void)ws_size;
  const float* x    = (const float*)d_in[0];
  const float* W    = (const float*)d_in[1];
  const float* bias = (const float*)d_in[2];
  const int* xl     = (const int*)d_in[3];
  const int* beam   = (const int*)d_in[5];
  const int* blankp = (const int*)d_in[6];
  const int* eosp   = (const int*)d_in[7];
  const int Ly = in_sizes[4] / Bb;
  const int CB = in_sizes[5] / Bb;

  float* Spart = (float*)d_ws;                                            // 1 MB
  float* selL  = (float*)((char*)d_ws + (size_t)0x100000);                // 2.03 MB
  unsigned char* Xfp = (unsigned char*)((char*)d_ws + (size_t)0x400000);  // 8 MB
  unsigned char* Wp  = (unsigned char*)((char*)d_ws + (size_t)0xC00000);  // 2 MB
  float* outf = (float*)d_out;

  kPre<<<2560, 256, 0, stream>>>(x, W, Xfp, Wp);
  kA<<<8192, 256, 0, stream>>>(Xfp, Wp, bias, beam, blankp, Spart, selL, CB);
  kC<<<Bb, 256, 0, stream>>>(selL, Spart, xl, beam, blankp, eosp, outf, Ly, CB);
}